// Round 7
// baseline (939.280 us; speedup 1.0000x reference)
//
#include <hip/hip_runtime.h>
#include <math.h>

typedef __attribute__((ext_vector_type(8))) short s16x8;
typedef __attribute__((ext_vector_type(4))) float f32x4;
typedef unsigned long long ull;

constexpr float LOG2E = 1.4426950408889634f;

__device__ __forceinline__ unsigned short f2bf(float f) {
  unsigned int x = __builtin_bit_cast(unsigned int, f);
  x += 0x7fffu + ((x >> 16) & 1u);          // RNE
  return (unsigned short)(x >> 16);
}
__device__ __forceinline__ float fexp2(float x) { return __builtin_amdgcn_exp2f(x); }
__device__ __forceinline__ float frcp(float x)  { return __builtin_amdgcn_rcpf(x); }

#define MFMA16(A, B, Cc) __builtin_amdgcn_mfma_f32_16x16x32_bf16((A), (B), (Cc), 0, 0, 0)

constexpr int TT = 512;
constexpr int NB = 1024;

// ---------------------------------------------------------------------------
// Per-layer scan, 16 batch rows/block, 8 waves. ONE barrier per step.
// Per step t:
//   top:   publish flag S=t-1 | DEFERRED ys store of h(t-1) (full step to
//          drain before the closing barrier's vmcnt(0) -> no store-ack stall)
//          | async flag read | prefetch x(t+1) into regs
//   body:  burst gx = bias + x(t)@Wih^T (x_s dbuf) | chain K=128 MFMA |
//          gates (trans) | h -> h_s dbuf | stage x(t+1) | absorb flag | sync.
// Flag semantics: S => ys steps [0,S) visible at MALL. h(t-1)'s store issues
// at top of t and is drained by t's closing __syncthreads, so top of t may
// publish S = t-1. Consumer needs S >= t+2 to prefetch x(t+1): ~3-step lag.
// ---------------------------------------------------------------------------
template <int DIN, bool FIRST, bool LAST>
__device__ __forceinline__ void scan_layer(
    unsigned short* x_s,                      // [2][16*DIN] swizzled dbuf
    unsigned short* h_s,                      // [2][16*128] swizzled dbuf
    float* b_s,                               // [512] pre-scaled bias
    const float* __restrict__ xin,            // FIRST: x [B][T][32] f32
    unsigned short* ys,                       // [T][B][128] bf16 pipe (in-place)
    const float* __restrict__ Wih, const float* __restrict__ Whh,
    const float* __restrict__ bias, float* __restrict__ hT,
    int* prog_in, int* prog_out, int bblk)
{
  constexpr int KTX = DIN / 32;               // 1 or 4 x k-tiles
  constexpr int XM  = (DIN == 32) ? 3 : 7;    // x-tile swizzle row mask
  const int tid = threadIdx.x;
  const int wv = tid >> 6, ln = tid & 63, l15 = ln & 15, lg = ln >> 4;
  const int row0 = bblk * 16;
  const int sr = tid >> 5, sc = tid & 31;     // staging coords: 16 rows x 32

  // ---- weights -> regs (bf16, pre-scaled by -log2e / 2log2e) ----
  s16x8 bfx[4][KTX], bfh[4][4];
#pragma unroll
  for (int j = 0; j < 4; ++j) {
    const float scale = (j == 2) ? (2.0f * LOG2E) : (-LOG2E);
    const int n = j * 128 + wv * 16 + l15;
#pragma unroll
    for (int kt = 0; kt < KTX; ++kt) {
      s16x8 f;
#pragma unroll
      for (int e = 0; e < 8; ++e) f[e] = (short)f2bf(Wih[n * DIN + kt * 32 + lg * 8 + e] * scale);
      bfx[j][kt] = f;
    }
#pragma unroll
    for (int kt = 0; kt < 4; ++kt) {
      s16x8 f;
#pragma unroll
      for (int e = 0; e < 8; ++e) f[e] = (short)f2bf(Whh[n * 128 + kt * 32 + lg * 8 + e] * scale);
      bfh[j][kt] = f;
    }
  }
  b_s[tid] = bias[tid] * ((tid >> 7) == 2 ? 2.0f * LOG2E : -LOG2E);
  for (int i = tid; i < 2 * 16 * 128; i += 512) h_s[i] = 0;   // h0 = 0

  // ---- prologue: acquire + stage x(0) into x_s[0] ----
  float xrf = 0.f;
  ull xrh = 0ull;
  int avail = 0;
  if (FIRST) {
    xrf = xin[(size_t)(row0 + sr) * (TT * 32) + sc];
    x_s[sr * DIN + (sc ^ ((sr & XM) << 3))] = f2bf(xrf);
  } else {
    int f;
    do { f = __hip_atomic_load(prog_in, __ATOMIC_RELAXED, __HIP_MEMORY_SCOPE_AGENT); } while (f < 1);
    avail = f;
    xrh = __hip_atomic_load(
        (ull*)ys + ((size_t)(row0 + sr) * 128 + sc * 4) / 4,
        __ATOMIC_RELAXED, __HIP_MEMORY_SCOPE_AGENT);
    *reinterpret_cast<ull*>(&x_s[sr * DIN + ((sc * 4) ^ ((sr & 7) << 3))]) = xrh;
  }
  __syncthreads();                            // x_s[0] + h0 + b_s visible

  float cst[4] = {0.f, 0.f, 0.f, 0.f};
  const int hcol = wv * 16 + lg * 4;          // my 4 cells (batch row l15)
  ull held = 0ull;                            // h(t-1) pack awaiting store

  for (int t = 0; t < TT; ++t) {
    // ---- top: publish lagged flag + deferred ys store of h(t-1) ----
    if (!LAST) {
      if (tid == 0 && t >= 2)
        __hip_atomic_store(prog_out, t - 1, __ATOMIC_RELAXED, __HIP_MEMORY_SCOPE_AGENT);
      if (t > 0)
        __hip_atomic_store(
            (ull*)ys + ((size_t)(t - 1) * (NB * 128) + (size_t)(row0 + l15) * 128 + hcol) / 4,
            held, __ATOMIC_RELAXED, __HIP_MEMORY_SCOPE_AGENT);
    }

    // ---- async flag read (absorbed before the closing barrier) ----
    int f_new = 0;
    if (!FIRST && t + 1 < TT)
      f_new = __hip_atomic_load(prog_in, __ATOMIC_RELAXED, __HIP_MEMORY_SCOPE_AGENT);

    // ---- prefetch x(t+1) into regs (steady path) ----
    bool pf = false;
    if (t + 1 < TT) {
      if (FIRST) {
        xrf = xin[(size_t)(row0 + sr) * (TT * 32) + (t + 1) * 32 + sc];
        pf = true;
      } else if (avail >= t + 2) {
        xrh = __hip_atomic_load(
            (ull*)ys + ((size_t)(t + 1) * (NB * 128) + (size_t)(row0 + sr) * 128 + sc * 4) / 4,
            __ATOMIC_RELAXED, __HIP_MEMORY_SCOPE_AGENT);
        pf = true;
      }
    }

    // ---- burst: gx[j] = bias + x(t)@Wih^T (off the chain) ----
    const unsigned short* xbuf = x_s + (t & 1) * (16 * DIN);
    f32x4 gx[4];
#pragma unroll
    for (int j = 0; j < 4; ++j)
      gx[j] = *reinterpret_cast<const f32x4*>(&b_s[j * 128 + wv * 16 + lg * 4]);
#pragma unroll
    for (int kt = 0; kt < KTX; ++kt) {
      const s16x8 xf = *reinterpret_cast<const s16x8*>(
          &xbuf[l15 * DIN + ((kt * 32 + lg * 8) ^ ((l15 & XM) << 3))]);
#pragma unroll
      for (int j = 0; j < 4; ++j) gx[j] = MFMA16(bfx[j][kt], xf, gx[j]);
    }

    // ---- slow path: flag shortfall -> spin + load ----
    if (!FIRST && t + 1 < TT && !pf) {
      int f = f_new;
      while (f < t + 2)
        f = __hip_atomic_load(prog_in, __ATOMIC_RELAXED, __HIP_MEMORY_SCOPE_AGENT);
      f_new = f;
      xrh = __hip_atomic_load(
          (ull*)ys + ((size_t)(t + 1) * (NB * 128) + (size_t)(row0 + sr) * 128 + sc * 4) / 4,
          __ATOMIC_RELAXED, __HIP_MEMORY_SCOPE_AGENT);
    }

    // ---- chain: K=128 recurrent MFMA on h(t) ----
    const unsigned short* hbuf = h_s + (t & 1) * (16 * 128);
    unsigned short* nbuf = h_s + ((t + 1) & 1) * (16 * 128);
    s16x8 afr[4];
#pragma unroll
    for (int kt = 0; kt < 4; ++kt)
      afr[kt] = *reinterpret_cast<const s16x8*>(
          &hbuf[l15 * 128 + ((kt * 32 + lg * 8) ^ ((l15 & 7) << 3))]);
#pragma unroll
    for (int kt = 0; kt < 4; ++kt)
#pragma unroll
      for (int j = 0; j < 4; ++j) gx[j] = MFMA16(bfh[j][kt], afr[kt], gx[j]);

    // ---- gates (pre-scaled: sigm = rcp(1+exp2(a)), tanh = 1-2rcp(1+exp2)) ----
    float hv[4];
#pragma unroll
    for (int r = 0; r < 4; ++r) {
      const float iv = frcp(1.0f + fexp2(gx[0][r]));
      const float fv = frcp(1.0f + fexp2(gx[1][r]));
      const float gv = 1.0f - 2.0f * frcp(1.0f + fexp2(gx[2][r]));
      const float ov = frcp(1.0f + fexp2(gx[3][r]));
      const float cn = fv * cst[r] + iv * gv;
      cst[r] = cn;
      const float th = 1.0f - 2.0f * frcp(1.0f + fexp2(cn * (2.0f * LOG2E)));
      hv[r] = ov * th;
    }
    unsigned int plo, phi;
    asm("v_cvt_pk_bf16_f32 %0, %1, %2" : "=v"(plo) : "v"(hv[0]), "v"(hv[1]));
    asm("v_cvt_pk_bf16_f32 %0, %1, %2" : "=v"(phi) : "v"(hv[2]), "v"(hv[3]));
    const ull hpack = (ull)plo | ((ull)phi << 32);

    *reinterpret_cast<ull*>(&nbuf[l15 * 128 + (hcol ^ ((l15 & 7) << 3))]) = hpack;

    if (!LAST) {
      held = hpack;                           // stored at top of iter t+1
    } else if (t == TT - 1) {
      f32x4 o = {hv[0], hv[1], hv[2], hv[3]};
      *reinterpret_cast<f32x4*>(&hT[(row0 + l15) * 128 + hcol]) = o;  // f32 for LN
    }

    // ---- stage x(t+1) into x_s[(t+1)&1] ----
    if (t + 1 < TT) {
      if (FIRST) {
        x_s[((t + 1) & 1) * (16 * DIN) + sr * DIN + (sc ^ ((sr & XM) << 3))] = f2bf(xrf);
      } else {
        *reinterpret_cast<ull*>(
            &x_s[((t + 1) & 1) * (16 * DIN) + sr * DIN + ((sc * 4) ^ ((sr & 7) << 3))]) = xrh;
      }
    }

    // ---- absorb async flag ----
    if (!FIRST && f_new > avail) avail = f_new;

    __syncthreads();  // h(t+1)+x_s visible; ys store of h(t-1) drained
  }

  // ---- epilogue: store h(TT-1), drain, publish all ----
  if (!LAST) {
    __hip_atomic_store(
        (ull*)ys + ((size_t)(TT - 1) * (NB * 128) + (size_t)(row0 + l15) * 128 + hcol) / 4,
        held, __ATOMIC_RELAXED, __HIP_MEMORY_SCOPE_AGENT);
    asm volatile("s_waitcnt vmcnt(0)" ::: "memory");
    __syncthreads();
    if (tid == 0)
      __hip_atomic_store(prog_out, TT, __ATOMIC_RELAXED, __HIP_MEMORY_SCOPE_AGENT);
  }
}

__global__ __launch_bounds__(512, 2) void lstm_fused(
    const float* __restrict__ x, unsigned short* ys,
    const float* __restrict__ Wih0, const float* __restrict__ Whh0, const float* __restrict__ b0,
    const float* __restrict__ Wih1, const float* __restrict__ Whh1, const float* __restrict__ b1,
    const float* __restrict__ Wih2, const float* __restrict__ Whh2, const float* __restrict__ b2,
    float* __restrict__ hT, int* prog)
{
  __shared__ unsigned short x_s[2 * 16 * 128];
  __shared__ unsigned short h_s[2 * 16 * 128];
  __shared__ float b_s[512];
  const int lay = blockIdx.x >> 6;
  const int bblk = blockIdx.x & 63;
  if (lay == 0) {
    scan_layer<32, true, false>(x_s, h_s, b_s, x, ys, Wih0, Whh0, b0, nullptr,
                                nullptr, &prog[(0 * 64 + bblk) * 16], bblk);
  } else if (lay == 1) {
    scan_layer<128, false, false>(x_s, h_s, b_s, nullptr, ys, Wih1, Whh1, b1, nullptr,
                                  &prog[(0 * 64 + bblk) * 16], &prog[(1 * 64 + bblk) * 16], bblk);
  } else {
    scan_layer<128, false, true>(x_s, h_s, b_s, nullptr, ys, Wih2, Whh2, b2, hT,
                                 &prog[(1 * 64 + bblk) * 16], nullptr, bblk);
  }
}

__global__ void init_flags(int* prog) {
  prog[threadIdx.x] = 0;
  prog[threadIdx.x + 1024] = 0;
}

// ---------------------------------------------------------------------------
// Head: LN + fc1 + fc2 + 4 heads + reparam + dec1 + dec2 + out. 4 rows/block.
// ---------------------------------------------------------------------------
__global__ __launch_bounds__(256) void head_kernel(
    const float* __restrict__ hT, const float* __restrict__ eps,
    const float* __restrict__ u, const float* __restrict__ choice,
    const float* __restrict__ ln_g, const float* __restrict__ ln_b,
    const float* __restrict__ fc1_W, const float* __restrict__ fc1_b,
    const float* __restrict__ fc2_W, const float* __restrict__ fc2_b,
    const float* __restrict__ mean_W, const float* __restrict__ mean_b,
    const float* __restrict__ logvar_W, const float* __restrict__ logvar_b,
    const float* __restrict__ scale_W, const float* __restrict__ scale_b,
    const float* __restrict__ shape_W, const float* __restrict__ shape_b,
    const float* __restrict__ dec1_W, const float* __restrict__ dec1_b,
    const float* __restrict__ dec2_W, const float* __restrict__ dec2_b,
    const float* __restrict__ out_W, const float* __restrict__ out_b,
    const float* __restrict__ pi_params, float* __restrict__ out)
{
  __shared__ float s_hn[4][128];
  __shared__ float s_a[4][128];
  __shared__ float s_b2[4][64];
  __shared__ float s_z[4][64];
  __shared__ float s_d1[4][128];
  __shared__ float s_d2[4][512];

  const int tid = threadIdx.x;
  const int gr0 = blockIdx.x * 4;

  { // LayerNorm: one wave per row
    const int wvr = tid >> 6, lnn = tid & 63;
    const float v0 = hT[(gr0 + wvr) * 128 + lnn];
    const float v1 = hT[(gr0 + wvr) * 128 + 64 + lnn];
    float s = v0 + v1, s2 = v0 * v0 + v1 * v1;
#pragma unroll
    for (int off = 32; off; off >>= 1) {
      s  += __shfl_xor(s, off, 64);
      s2 += __shfl_xor(s2, off, 64);
    }
    const float mu  = s * (1.f / 128.f);
    const float var = s2 * (1.f / 128.f) - mu * mu;
    const float rs  = rsqrtf(var + 1e-5f);
    s_hn[wvr][lnn]      = (v0 - mu) * rs * ln_g[lnn]      + ln_b[lnn];
    s_hn[wvr][lnn + 64] = (v1 - mu) * rs * ln_g[lnn + 64] + ln_b[lnn + 64];
  }
  __syncthreads();
#pragma unroll
  for (int p = 0; p < 2; ++p) { // fc1 (128x128) + relu
    const int idx = tid + p * 256, row = idx >> 7, col = idx & 127;
    const float* w = fc1_W + col * 128;
    float a = fc1_b[col];
    for (int k = 0; k < 128; k += 4)
      a += s_hn[row][k] * w[k] + s_hn[row][k + 1] * w[k + 1] +
           s_hn[row][k + 2] * w[k + 2] + s_hn[row][k + 3] * w[k + 3];
    s_a[row][col] = fmaxf(a, 0.f);
  }
  __syncthreads();
  { // fc2 (64x128) + relu
    const int row = tid >> 6, col = tid & 63;
    const float* w = fc2_W + col * 128;
    float a = fc2_b[col];
    for (int k = 0; k < 128; ++k) a += s_a[row][k] * w[k];
    s_b2[row][col] = fmaxf(a, 0.f);
  }
  __syncthreads();
  { // 4 heads + reparameterize
    const int row = tid >> 6, c = tid & 63;
    const int gr = gr0 + row;
    float am = mean_b[c], al = logvar_b[c], as_ = scale_b[c], ah = shape_b[c];
    for (int k = 0; k < 64; ++k) {
      const float hv = s_b2[row][k];
      am  += hv * mean_W[c * 64 + k];
      al  += hv * logvar_W[c * 64 + k];
      as_ += hv * scale_W[c * 64 + k];
      ah  += hv * shape_W[c * 64 + k];
    }
    const float zsc = fexp2(as_ * LOG2E);
    const float zsh = fmaxf(ah, 1e-6f);
    out[131072 + gr * 64 + c] = am;
    out[196608 + gr * 64 + c] = al;
    out[262144 + gr * 64 + c] = zsc;
    out[327680 + gr * 64 + c] = zsh;
    const float ev = eps[gr * 64 + c], uv = u[gr * 64 + c], cv = choice[gr];
    const float zg = am + ev * fexp2(0.72134752044448170f * al);  // exp(0.5*logvar)
    const float p0 = pi_params[0], p1 = pi_params[1];
    const float pi0 = 1.f / (1.f + expf(p1 - p0));
    const float tq = -zsh * logf(1.f - uv);                       // expm1: no cancel
    const float zp = zsc * frcp(zsh) * expm1f(tq);
    s_z[row][c] = (cv < pi0) ? zg : zp;
  }
  __syncthreads();
#pragma unroll
  for (int p = 0; p < 2; ++p) { // dec1 (128x64) + relu
    const int idx = tid + p * 256, row = idx >> 7, col = idx & 127;
    const float* w = dec1_W + col * 64;
    float a = dec1_b[col];
    for (int k = 0; k < 64; ++k) a += s_z[row][k] * w[k];
    s_d1[row][col] = fmaxf(a, 0.f);
  }
  __syncthreads();
  for (int o = tid; o < 2000; o += 256) { // dec2 (500x128) + relu
    const int row = o / 500, col = o % 500;
    const float* w = dec2_W + col * 128;
    float a = dec2_b[col];
    for (int k = 0; k < 128; ++k) a += s_d1[row][k] * w[k];
    s_d2[row][col] = fmaxf(a, 0.f);
  }
  __syncthreads();
#pragma unroll
  for (int p = 0; p < 2; ++p) { // out (128x500)
    const int idx = tid + p * 256, row = idx >> 7, col = idx & 127;
    const float* w = out_W + col * 500;
    float a = out_b[col];
    for (int k = 0; k < 500; ++k) a += s_d2[row][k] * w[k];
    out[(gr0 + row) * 128 + col] = a;
  }
}

// ---------------------------------------------------------------------------
extern "C" void kernel_launch(void* const* d_in, const int* in_sizes, int n_in,
                              void* d_out, int out_size, void* d_ws, size_t ws_size,
                              hipStream_t stream) {
  const float* x      = (const float*)d_in[0];
  const float* eps    = (const float*)d_in[1];
  const float* u      = (const float*)d_in[2];
  const float* choice = (const float*)d_in[3];
  const float* Wih0 = (const float*)d_in[4],  *Whh0 = (const float*)d_in[5],  *b0 = (const float*)d_in[6];
  const float* Wih1 = (const float*)d_in[7],  *Whh1 = (const float*)d_in[8],  *b1 = (const float*)d_in[9];
  const float* Wih2 = (const float*)d_in[10], *Whh2 = (const float*)d_in[11], *b2 = (const float*)d_in[12];
  const float* ln_g = (const float*)d_in[13], *ln_b = (const float*)d_in[14];
  const float* fc1_W = (const float*)d_in[15], *fc1_b = (const float*)d_in[16];
  const float* fc2_W = (const float*)d_in[17], *fc2_b = (const float*)d_in[18];
  const float* mean_W = (const float*)d_in[19], *mean_b = (const float*)d_in[20];
  const float* logvar_W = (const float*)d_in[21], *logvar_b = (const float*)d_in[22];
  const float* scale_W = (const float*)d_in[23], *scale_b = (const float*)d_in[24];
  const float* shape_W = (const float*)d_in[25], *shape_b = (const float*)d_in[26];
  const float* dec1_W = (const float*)d_in[27], *dec1_b = (const float*)d_in[28];
  const float* dec2_W = (const float*)d_in[29], *dec2_b = (const float*)d_in[30];
  const float* out_W = (const float*)d_in[31], *out_b = (const float*)d_in[32];
  const float* pi_params = (const float*)d_in[33];

  unsigned short* ys = (unsigned short*)d_ws;                        // 128 MiB
  float* hT  = (float*)((char*)d_ws + (size_t)512 * 1024 * 128 * 2); // 512 KiB
  int*   prog = (int*)((char*)d_ws + (size_t)512 * 1024 * 128 * 2 + (size_t)1024 * 128 * 4);

  init_flags<<<1, 1024, 0, stream>>>(prog);
  lstm_fused<<<192, 512, 0, stream>>>(x, ys, Wih0, Whh0, b0, Wih1, Whh1, b1,
                                      Wih2, Whh2, b2, hT, prog);
  head_kernel<<<256, 256, 0, stream>>>(hT, eps, u, choice, ln_g, ln_b,
      fc1_W, fc1_b, fc2_W, fc2_b, mean_W, mean_b, logvar_W, logvar_b,
      scale_W, scale_b, shape_W, shape_b, dec1_W, dec1_b, dec2_W, dec2_b,
      out_W, out_b, pi_params, (float*)d_out);
}

// Round 9
// 691.386 us; speedup vs baseline: 1.3585x; 1.3585x over previous
//
#include <hip/hip_runtime.h>
#include <math.h>

typedef __attribute__((ext_vector_type(8))) short s16x8;
typedef __attribute__((ext_vector_type(4))) float f32x4;
typedef unsigned long long ull;

constexpr float LOG2E = 1.4426950408889634f;

__device__ __forceinline__ unsigned short f2bf(float f) {
  unsigned int x = __builtin_bit_cast(unsigned int, f);
  x += 0x7fffu + ((x >> 16) & 1u);          // RNE
  return (unsigned short)(x >> 16);
}
__device__ __forceinline__ float fexp2(float x) { return __builtin_amdgcn_exp2f(x); }
__device__ __forceinline__ float frcp(float x)  { return __builtin_amdgcn_rcpf(x); }

#define MFMA16(A, B, Cc) __builtin_amdgcn_mfma_f32_16x16x32_bf16((A), (B), (Cc), 0, 0, 0)

constexpr int TT = 512;
constexpr int NB = 1024;

// Shared-denominator LSTM cell: 7 trans (5 exp2, 2 rcp) instead of 10.
// Inputs pre-scaled: ai,af,ao = -log2e*a ; ag = +2log2e*a.
//   f=1/(1+F), i=1/(1+I), g=(G-1)/(G+1):  c' = [c*(1+I)(1+G)+(G-1)(1+F)]/D,
//   D=(1+F)(1+I)(1+G);  h = (E-1)/[(1+O)(E+1)], E=2^(2log2e*c').
// Clamps keep products < FLT_MAX; the final division renormalizes.
__device__ __forceinline__ float lstm_cell(float ai, float af, float ag, float ao,
                                           float& c) {
  const float F = fexp2(fminf(af, 29.f));
  const float I = fexp2(fminf(ai, 29.f));
  const float G = fexp2(fminf(ag, 29.f));
  const float O = fexp2(fminf(ao, 29.f));
  const float P   = (1.f + I) * (1.f + G);
  const float num = c * P + (G - 1.f) * (1.f + F);
  const float cn  = num * frcp((1.f + F) * P);
  c = cn;
  const float E = fexp2(fminf(cn * (2.f * LOG2E), 60.f));
  return (E - 1.f) * frcp((1.f + O) * (E + 1.f));
}

// ---------------------------------------------------------------------------
// Per-layer scan, 16 rows/block, 8 waves, 2 barriers per 2-step chunk (the
// proven 655us sync structure). New vs baseline:
//  * gx (bias + x@Wih^T) for chunk k+1 is burst-computed by MFMAs placed in
//    chunk k's step-1 GATE region -> burst issue hides in trans stalls.
//  * x tile staged at chunk TOP from regs loaded one chunk earlier (single
//    [2][16][DIN] buffer; each tile read exactly once, by the early burst).
//  * gx/x regs ping-pong via 2-chunk unrolled loop (static indexing).
// Flag S (steps): ys [0,S) visible at MALL. Publish S=t0 at chunk top
// (stores <= t0-1 drained by previous closing barrier). Consumer loads
// chunk c+2 at top -> needs S >= t0+6 (lag 6; producers never wait -> no
// deadlock).
// ---------------------------------------------------------------------------
template <int DIN, bool FIRST, bool LAST>
__device__ __forceinline__ void scan_layer(
    unsigned short* x_s,                      // [2][16][DIN] swizzled
    unsigned short* h_s,                      // [2][16][128] swizzled dbuf
    float* b_s,                               // [512] pre-scaled bias
    const float* __restrict__ xin,            // FIRST: x [B][T][32] f32
    unsigned short* ys,                       // [T][B][128] bf16 pipe (in-place)
    const float* __restrict__ Wih, const float* __restrict__ Whh,
    const float* __restrict__ bias, float* __restrict__ hT,
    int* prog_in, int* prog_out, int bblk)
{
  constexpr int KTX = DIN / 32;               // 1 or 4 x k-tiles
  constexpr int XM  = (DIN == 32) ? 3 : 7;    // x-tile swizzle row mask
  const int tid = threadIdx.x;
  const int wv = tid >> 6, ln = tid & 63, l15 = ln & 15, lg = ln >> 4;
  const int row0 = bblk * 16;
  const int sr = tid >> 5, sc = tid & 31;

  // ---- weights -> regs (bf16, pre-scaled by -log2e / 2log2e) ----
  s16x8 bfx[4][KTX], bfh[4][4];
#pragma unroll
  for (int j = 0; j < 4; ++j) {
    const float scl = (j == 2) ? (2.0f * LOG2E) : (-LOG2E);
    const int n = j * 128 + wv * 16 + l15;
#pragma unroll
    for (int kt = 0; kt < KTX; ++kt) {
      s16x8 f;
#pragma unroll
      for (int e = 0; e < 8; ++e) f[e] = (short)f2bf(Wih[n * DIN + kt * 32 + lg * 8 + e] * scl);
      bfx[j][kt] = f;
    }
#pragma unroll
    for (int kt = 0; kt < 4; ++kt) {
      s16x8 f;
#pragma unroll
      for (int e = 0; e < 8; ++e) f[e] = (short)f2bf(Whh[n * 128 + kt * 32 + lg * 8 + e] * scl);
      bfh[j][kt] = f;
    }
  }
  b_s[tid] = bias[tid] * ((tid >> 7) == 2 ? 2.0f * LOG2E : -LOG2E);
  for (int i = tid; i < 2 * 16 * 128; i += 512) h_s[i] = 0;   // h0 = 0

  // ---- prologue: stage chunk 0, hold chunk 1 in regs ----
  float xfA[2], xfB[2];
  ull   xuA[2], xuB[2];
  int avail = 0;
  if (FIRST) {
#pragma unroll
    for (int s = 0; s < 2; ++s) {
      const float v = xin[(size_t)(row0 + sr) * (TT * 32) + s * 32 + sc];
      x_s[s * (16 * DIN) + sr * DIN + (sc ^ ((sr & XM) << 3))] = f2bf(v);
      xfA[s] = xin[(size_t)(row0 + sr) * (TT * 32) + (2 + s) * 32 + sc];
    }
    xuA[0] = xuA[1] = xuB[0] = xuB[1] = 0;
    xfB[0] = xfB[1] = 0.f;
  } else {
    int f;
    do { f = __hip_atomic_load(prog_in, __ATOMIC_RELAXED, __HIP_MEMORY_SCOPE_AGENT); } while (f < 4);
    avail = f;
#pragma unroll
    for (int s = 0; s < 2; ++s) {
      const ull v = __hip_atomic_load(
          (ull*)ys + ((size_t)s * (NB * 128) + (size_t)(row0 + sr) * 128 + sc * 4) / 4,
          __ATOMIC_RELAXED, __HIP_MEMORY_SCOPE_AGENT);
      *reinterpret_cast<ull*>(&x_s[s * (16 * DIN) + sr * DIN + ((sc * 4) ^ ((sr & 7) << 3))]) = v;
      xuA[s] = __hip_atomic_load(
          (ull*)ys + ((size_t)(2 + s) * (NB * 128) + (size_t)(row0 + sr) * 128 + sc * 4) / 4,
          __ATOMIC_RELAXED, __HIP_MEMORY_SCOPE_AGENT);
    }
    xfA[0] = xfA[1] = xfB[0] = xfB[1] = 0.f;
    xuB[0] = xuB[1] = 0;
  }
  __syncthreads();                            // x_s(chunk0) + h0 + b_s visible

  // ---- prologue burst: gx for chunk 0 ----
  f32x4 gxA[2][4], gxB[2][4];
#pragma unroll
  for (int s = 0; s < 2; ++s) {
#pragma unroll
    for (int j = 0; j < 4; ++j)
      gxA[s][j] = *reinterpret_cast<const f32x4*>(&b_s[j * 128 + wv * 16 + lg * 4]);
#pragma unroll
    for (int kt = 0; kt < KTX; ++kt) {
      const s16x8 xf = *reinterpret_cast<const s16x8*>(
          &x_s[s * (16 * DIN) + l15 * DIN + ((kt * 32 + lg * 8) ^ ((l15 & XM) << 3))]);
#pragma unroll
      for (int j = 0; j < 4; ++j) gxA[s][j] = MFMA16(bfx[j][kt], xf, gxA[s][j]);
    }
  }

  float cst[4] = {0.f, 0.f, 0.f, 0.f};
  const int hcol = wv * 16 + lg * 4;          // my 4 cells (batch row l15)

  auto chunk = [&](int t0, f32x4 (&gxc)[2][4], f32x4 (&gxn)[2][4],
                   float (&xf_st)[2], ull (&xu_st)[2],
                   float (&xf_nx)[2], ull (&xu_nx)[2]) {
    // ---- top: publish lagged flag ----
    if (!LAST && tid == 0 && t0 > 0)
      __hip_atomic_store(prog_out, t0, __ATOMIC_RELAXED, __HIP_MEMORY_SCOPE_AGENT);
    int f_new = 0;
    if (!FIRST && t0 + 4 < TT) {
      if (avail < t0 + 6) {                   // slow path (startup/hiccup)
        int f;
        do { f = __hip_atomic_load(prog_in, __ATOMIC_RELAXED, __HIP_MEMORY_SCOPE_AGENT); } while (f < t0 + 6);
        avail = f;
      }
      f_new = __hip_atomic_load(prog_in, __ATOMIC_RELAXED, __HIP_MEMORY_SCOPE_AGENT);
    }
    // ---- stage x(chunk c+1) from regs (loaded one chunk ago) ----
    if (t0 + 2 < TT) {
      if constexpr (FIRST) {
#pragma unroll
        for (int s = 0; s < 2; ++s)
          x_s[s * (16 * DIN) + sr * DIN + (sc ^ ((sr & XM) << 3))] = f2bf(xf_st[s]);
      } else {
#pragma unroll
        for (int s = 0; s < 2; ++s)
          *reinterpret_cast<ull*>(
              &x_s[s * (16 * DIN) + sr * DIN + ((sc * 4) ^ ((sr & 7) << 3))]) = xu_st[s];
      }
    }
    // ---- load x(chunk c+2) -> nx regs (2-step cover) ----
    if (t0 + 4 < TT) {
      if constexpr (FIRST) {
#pragma unroll
        for (int s = 0; s < 2; ++s)
          xf_nx[s] = xin[(size_t)(row0 + sr) * (TT * 32) + (t0 + 4 + s) * 32 + sc];
      } else {
#pragma unroll
        for (int s = 0; s < 2; ++s)
          xu_nx[s] = __hip_atomic_load(
              (ull*)ys + ((size_t)(t0 + 4 + s) * (NB * 128) + (size_t)(row0 + sr) * 128 + sc * 4) / 4,
              __ATOMIC_RELAXED, __HIP_MEMORY_SCOPE_AGENT);
      }
    }

    // ---- step 0: t = t0 (even) ----
    {
      const unsigned short* hbuf = h_s;                   // t0&1 == 0
      unsigned short* hnb = h_s + 16 * 128;
      s16x8 afr[4];
#pragma unroll
      for (int kt = 0; kt < 4; ++kt)
        afr[kt] = *reinterpret_cast<const s16x8*>(
            &hbuf[l15 * 128 + ((kt * 32 + lg * 8) ^ ((l15 & 7) << 3))]);
#pragma unroll
      for (int kt = 0; kt < 4; ++kt)
#pragma unroll
        for (int j = 0; j < 4; ++j) gxc[0][j] = MFMA16(bfh[j][kt], afr[kt], gxc[0][j]);

      float hv[4];
#pragma unroll
      for (int r = 0; r < 4; ++r)
        hv[r] = lstm_cell(gxc[0][0][r], gxc[0][1][r], gxc[0][2][r], gxc[0][3][r], cst[r]);
      unsigned int plo, phi;
      asm("v_cvt_pk_bf16_f32 %0, %1, %2" : "=v"(plo) : "v"(hv[0]), "v"(hv[1]));
      asm("v_cvt_pk_bf16_f32 %0, %1, %2" : "=v"(phi) : "v"(hv[2]), "v"(hv[3]));
      const ull hpack = (ull)plo | ((ull)phi << 32);
      *reinterpret_cast<ull*>(&hnb[l15 * 128 + (hcol ^ ((l15 & 7) << 3))]) = hpack;
      if (!LAST)
        __hip_atomic_store(
            (ull*)ys + ((size_t)t0 * (NB * 128) + (size_t)(row0 + l15) * 128 + hcol) / 4,
            hpack, __ATOMIC_RELAXED, __HIP_MEMORY_SCOPE_AGENT);
      __syncthreads();                        // h(t0+1) + staged x visible
    }

    // ---- step 1: t = t0+1 ; burst for chunk c+1 hides in gate stalls ----
    {
      const unsigned short* hbuf = h_s + 16 * 128;
      unsigned short* hnb = h_s;
      s16x8 afr[4];
#pragma unroll
      for (int kt = 0; kt < 4; ++kt)
        afr[kt] = *reinterpret_cast<const s16x8*>(
            &hbuf[l15 * 128 + ((kt * 32 + lg * 8) ^ ((l15 & 7) << 3))]);
#pragma unroll
      for (int kt = 0; kt < 4; ++kt)
#pragma unroll
        for (int j = 0; j < 4; ++j) gxc[1][j] = MFMA16(bfh[j][kt], afr[kt], gxc[1][j]);

      // independent burst: gx for next chunk (MFMA issue fills trans stalls)
      if (t0 + 2 < TT) {
#pragma unroll
        for (int s = 0; s < 2; ++s) {
#pragma unroll
          for (int j = 0; j < 4; ++j)
            gxn[s][j] = *reinterpret_cast<const f32x4*>(&b_s[j * 128 + wv * 16 + lg * 4]);
#pragma unroll
          for (int kt = 0; kt < KTX; ++kt) {
            const s16x8 xf = *reinterpret_cast<const s16x8*>(
                &x_s[s * (16 * DIN) + l15 * DIN + ((kt * 32 + lg * 8) ^ ((l15 & XM) << 3))]);
#pragma unroll
            for (int j = 0; j < 4; ++j) gxn[s][j] = MFMA16(bfx[j][kt], xf, gxn[s][j]);
          }
        }
      }

      float hv[4];
#pragma unroll
      for (int r = 0; r < 4; ++r)
        hv[r] = lstm_cell(gxc[1][0][r], gxc[1][1][r], gxc[1][2][r], gxc[1][3][r], cst[r]);
      unsigned int plo, phi;
      asm("v_cvt_pk_bf16_f32 %0, %1, %2" : "=v"(plo) : "v"(hv[0]), "v"(hv[1]));
      asm("v_cvt_pk_bf16_f32 %0, %1, %2" : "=v"(phi) : "v"(hv[2]), "v"(hv[3]));
      const ull hpack = (ull)plo | ((ull)phi << 32);
      *reinterpret_cast<ull*>(&hnb[l15 * 128 + (hcol ^ ((l15 & 7) << 3))]) = hpack;
      if (!LAST) {
        __hip_atomic_store(
            (ull*)ys + ((size_t)(t0 + 1) * (NB * 128) + (size_t)(row0 + l15) * 128 + hcol) / 4,
            hpack, __ATOMIC_RELAXED, __HIP_MEMORY_SCOPE_AGENT);
      } else if (t0 + 1 == TT - 1) {
        f32x4 o = {hv[0], hv[1], hv[2], hv[3]};
        *reinterpret_cast<f32x4*>(&hT[(row0 + l15) * 128 + hcol]) = o;  // f32 for LN
      }
      if (!FIRST && f_new > avail) avail = f_new;
      __syncthreads();                        // h(t0+2) visible; ys stores drained
    }
  };

  for (int t0 = 0; t0 < TT; t0 += 4) {        // 2-chunk unroll: gx/x ping-pong
    chunk(t0,     gxA, gxB, xfA, xuA, xfB, xuB);
    chunk(t0 + 2, gxB, gxA, xfB, xuB, xfA, xuA);
  }

  if (!LAST) {
    asm volatile("s_waitcnt vmcnt(0)" ::: "memory");
    __syncthreads();
    if (tid == 0)
      __hip_atomic_store(prog_out, TT, __ATOMIC_RELAXED, __HIP_MEMORY_SCOPE_AGENT);
  }
}

__global__ __launch_bounds__(512, 2) void lstm_fused(
    const float* __restrict__ x, unsigned short* ys,
    const float* __restrict__ Wih0, const float* __restrict__ Whh0, const float* __restrict__ b0,
    const float* __restrict__ Wih1, const float* __restrict__ Whh1, const float* __restrict__ b1,
    const float* __restrict__ Wih2, const float* __restrict__ Whh2, const float* __restrict__ b2,
    float* __restrict__ hT, int* prog)
{
  __shared__ unsigned short x_s[2 * 16 * 128];
  __shared__ unsigned short h_s[2 * 16 * 128];
  __shared__ float b_s[512];
  const int lay = blockIdx.x >> 6;
  const int bblk = blockIdx.x & 63;
  if (lay == 0) {
    scan_layer<32, true, false>(x_s, h_s, b_s, x, ys, Wih0, Whh0, b0, nullptr,
                                nullptr, &prog[(0 * 64 + bblk) * 16], bblk);
  } else if (lay == 1) {
    scan_layer<128, false, false>(x_s, h_s, b_s, nullptr, ys, Wih1, Whh1, b1, nullptr,
                                  &prog[(0 * 64 + bblk) * 16], &prog[(1 * 64 + bblk) * 16], bblk);
  } else {
    scan_layer<128, false, true>(x_s, h_s, b_s, nullptr, ys, Wih2, Whh2, b2, hT,
                                 &prog[(1 * 64 + bblk) * 16], nullptr, bblk);
  }
}

__global__ void init_flags(int* prog) {
  prog[threadIdx.x] = 0;
  prog[threadIdx.x + 1024] = 0;
}

// ---------------------------------------------------------------------------
// Head: LN + fc1 + fc2 + 4 heads + reparam + dec1 + dec2 + out. 4 rows/block.
// ---------------------------------------------------------------------------
__global__ __launch_bounds__(256) void head_kernel(
    const float* __restrict__ hT, const float* __restrict__ eps,
    const float* __restrict__ u, const float* __restrict__ choice,
    const float* __restrict__ ln_g, const float* __restrict__ ln_b,
    const float* __restrict__ fc1_W, const float* __restrict__ fc1_b,
    const float* __restrict__ fc2_W, const float* __restrict__ fc2_b,
    const float* __restrict__ mean_W, const float* __restrict__ mean_b,
    const float* __restrict__ logvar_W, const float* __restrict__ logvar_b,
    const float* __restrict__ scale_W, const float* __restrict__ scale_b,
    const float* __restrict__ shape_W, const float* __restrict__ shape_b,
    const float* __restrict__ dec1_W, const float* __restrict__ dec1_b,
    const float* __restrict__ dec2_W, const float* __restrict__ dec2_b,
    const float* __restrict__ out_W, const float* __restrict__ out_b,
    const float* __restrict__ pi_params, float* __restrict__ out)
{
  __shared__ float s_hn[4][128];
  __shared__ float s_a[4][128];
  __shared__ float s_b2[4][64];
  __shared__ float s_z[4][64];
  __shared__ float s_d1[4][128];
  __shared__ float s_d2[4][512];

  const int tid = threadIdx.x;
  const int gr0 = blockIdx.x * 4;

  { // LayerNorm: one wave per row
    const int wvr = tid >> 6, lnn = tid & 63;
    const float v0 = hT[(gr0 + wvr) * 128 + lnn];
    const float v1 = hT[(gr0 + wvr) * 128 + 64 + lnn];
    float s = v0 + v1, s2 = v0 * v0 + v1 * v1;
#pragma unroll
    for (int off = 32; off; off >>= 1) {
      s  += __shfl_xor(s, off, 64);
      s2 += __shfl_xor(s2, off, 64);
    }
    const float mu  = s * (1.f / 128.f);
    const float var = s2 * (1.f / 128.f) - mu * mu;
    const float rs  = rsqrtf(var + 1e-5f);
    s_hn[wvr][lnn]      = (v0 - mu) * rs * ln_g[lnn]      + ln_b[lnn];
    s_hn[wvr][lnn + 64] = (v1 - mu) * rs * ln_g[lnn + 64] + ln_b[lnn + 64];
  }
  __syncthreads();
#pragma unroll
  for (int p = 0; p < 2; ++p) { // fc1 (128x128) + relu
    const int idx = tid + p * 256, row = idx >> 7, col = idx & 127;
    const float* w = fc1_W + col * 128;
    float a = fc1_b[col];
    for (int k = 0; k < 128; k += 4)
      a += s_hn[row][k] * w[k] + s_hn[row][k + 1] * w[k + 1] +
           s_hn[row][k + 2] * w[k + 2] + s_hn[row][k + 3] * w[k + 3];
    s_a[row][col] = fmaxf(a, 0.f);
  }
  __syncthreads();
  { // fc2 (64x128) + relu
    const int row = tid >> 6, col = tid & 63;
    const float* w = fc2_W + col * 128;
    float a = fc2_b[col];
    for (int k = 0; k < 128; ++k) a += s_a[row][k] * w[k];
    s_b2[row][col] = fmaxf(a, 0.f);
  }
  __syncthreads();
  { // 4 heads + reparameterize
    const int row = tid >> 6, c = tid & 63;
    const int gr = gr0 + row;
    float am = mean_b[c], al = logvar_b[c], as_ = scale_b[c], ah = shape_b[c];
    for (int k = 0; k < 64; ++k) {
      const float hv = s_b2[row][k];
      am  += hv * mean_W[c * 64 + k];
      al  += hv * logvar_W[c * 64 + k];
      as_ += hv * scale_W[c * 64 + k];
      ah  += hv * shape_W[c * 64 + k];
    }
    const float zsc = fexp2(as_ * LOG2E);
    const float zsh = fmaxf(ah, 1e-6f);
    out[131072 + gr * 64 + c] = am;
    out[196608 + gr * 64 + c] = al;
    out[262144 + gr * 64 + c] = zsc;
    out[327680 + gr * 64 + c] = zsh;
    const float ev = eps[gr * 64 + c], uv = u[gr * 64 + c], cv = choice[gr];
    const float zg = am + ev * fexp2(0.72134752044448170f * al);  // exp(0.5*logvar)
    const float p0 = pi_params[0], p1 = pi_params[1];
    const float pi0 = 1.f / (1.f + expf(p1 - p0));
    const float tq = -zsh * logf(1.f - uv);                       // expm1: no cancel
    const float zp = zsc * frcp(zsh) * expm1f(tq);
    s_z[row][c] = (cv < pi0) ? zg : zp;
  }
  __syncthreads();
#pragma unroll
  for (int p = 0; p < 2; ++p) { // dec1 (128x64) + relu
    const int idx = tid + p * 256, row = idx >> 7, col = idx & 127;
    const float* w = dec1_W + col * 64;
    float a = dec1_b[col];
    for (int k = 0; k < 64; ++k) a += s_z[row][k] * w[k];
    s_d1[row][col] = fmaxf(a, 0.f);
  }
  __syncthreads();
  for (int o = tid; o < 2000; o += 256) { // dec2 (500x128) + relu
    const int row = o / 500, col = o % 500;
    const float* w = dec2_W + col * 128;
    float a = dec2_b[col];
    for (int k = 0; k < 128; ++k) a += s_d1[row][k] * w[k];
    s_d2[row][col] = fmaxf(a, 0.f);
  }
  __syncthreads();
#pragma unroll
  for (int p = 0; p < 2; ++p) { // out (128x500)
    const int idx = tid + p * 256, row = idx >> 7, col = idx & 127;
    const float* w = out_W + col * 500;
    float a = out_b[col];
    for (int k = 0; k < 500; ++k) a += s_d2[row][k] * w[k];
    out[(gr0 + row) * 128 + col] = a;
  }
}

// ---------------------------------------------------------------------------
extern "C" void kernel_launch(void* const* d_in, const int* in_sizes, int n_in,
                              void* d_out, int out_size, void* d_ws, size_t ws_size,
                              hipStream_t stream) {
  const float* x      = (const float*)d_in[0];
  const float* eps    = (const float*)d_in[1];
  const float* u      = (const float*)d_in[2];
  const float* choice = (const float*)d_in[3];
  const float* Wih0 = (const float*)d_in[4],  *Whh0 = (const float*)d_in[5],  *b0 = (const float*)d_in[6];
  const float* Wih1 = (const float*)d_in[7],  *Whh1 = (const float*)d_in[8],  *b1 = (const float*)d_in[9];
  const float* Wih2 = (const float*)d_in[10], *Whh2 = (const float*)d_in[11], *b2 = (const float*)d_in[12];
  const float* ln_g = (const float*)d_in[13], *ln_b = (const float*)d_in[14];
  const float* fc1_W = (const float*)d_in[15], *fc1_b = (const float*)d_in[16];
  const float* fc2_W = (const float*)d_in[17], *fc2_b = (const float*)d_in[18];
  const float* mean_W = (const float*)d_in[19], *mean_b = (const float*)d_in[20];
  const float* logvar_W = (const float*)d_in[21], *logvar_b = (const float*)d_in[22];
  const float* scale_W = (const float*)d_in[23], *scale_b = (const float*)d_in[24];
  const float* shape_W = (const float*)d_in[25], *shape_b = (const float*)d_in[26];
  const float* dec1_W = (const float*)d_in[27], *dec1_b = (const float*)d_in[28];
  const float* dec2_W = (const float*)d_in[29], *dec2_b = (const float*)d_in[30];
  const float* out_W = (const float*)d_in[31], *out_b = (const float*)d_in[32];
  const float* pi_params = (const float*)d_in[33];

  unsigned short* ys = (unsigned short*)d_ws;                        // 128 MiB
  float* hT  = (float*)((char*)d_ws + (size_t)512 * 1024 * 128 * 2); // 512 KiB
  int*   prog = (int*)((char*)d_ws + (size_t)512 * 1024 * 128 * 2 + (size_t)1024 * 128 * 4);

  init_flags<<<1, 1024, 0, stream>>>(prog);
  lstm_fused<<<192, 512, 0, stream>>>(x, ys, Wih0, Whh0, b0, Wih1, Whh1, b1,
                                      Wih2, Whh2, b2, hT, prog);
  head_kernel<<<256, 256, 0, stream>>>(hT, eps, u, choice, ln_g, ln_b,
      fc1_W, fc1_b, fc2_W, fc2_b, mean_W, mean_b, logvar_W, logvar_b,
      scale_W, scale_b, shape_W, shape_b, dec1_W, dec1_b, dec2_W, dec2_b,
      out_W, out_b, pi_params, (float*)d_out);
}